// Round 12
// baseline (5964.791 us; speedup 1.0000x reference)
//
#include <hip/hip_runtime.h>

#define N_NODES 50000
#define N_EDGES 800000
#define DIM 96

// GEMM tile: 256 threads, 128-row x 96-col block tile.
// thread (tx = t&7, ty = t>>3) owns rows [4ty,4ty+4) x cols [12tx, 12tx+12).
#define BM 128
#define BK 48
#define APAD 52   // A row stride (floats): 208B, 16B-aligned.
#define HPAD 100  // H row stride (floats): 400B, 16B-aligned.

// CSR scratch layout (int offsets) inside the out_he region, which is
// overwritten by edge_mlp_kernel at the very end of the launch sequence.
#define SC_CNT 0           // [50000) histogram / per-node degree
#define SC_OFF 50000       // [50001) exclusive prefix (CSR row offsets)
#define SC_CUR 100016      // [50000) fill cursors
#define SC_BSUM 150016     // [256)   per-block partial sums for the scan
#define SC_EIDX 150528     // [800000) edge ids sorted by destination
#define NBLK_SCAN 196      // ceil(50000/256)

#define FMA4(C, A, W)        \
  C.x = fmaf(A, W.x, C.x);   \
  C.y = fmaf(A, W.y, C.y);   \
  C.z = fmaf(A, W.z, C.z);   \
  C.w = fmaf(A, W.w, C.w)

#define BIAS_RELU4(C, B)          \
  C.x = fmaxf(C.x + B.x, 0.0f);   \
  C.y = fmaxf(C.y + B.y, 0.0f);   \
  C.z = fmaxf(C.z + B.z, 0.0f);   \
  C.w = fmaxf(C.w + B.w, 0.0f)

#define BIAS4(C, B) \
  C.x += B.x;       \
  C.y += B.y;       \
  C.z += B.z;       \
  C.w += B.w

// One k-step: 3 W float4 reads (8-way broadcast, bank-conflict-free) feed
// 48 FMAs across the 4-row x 12-col register tile.
#define KQ(KK, A0, A1, A2, A3)                                               \
  {                                                                          \
    const float4 w0 =                                                        \
        *reinterpret_cast<const float4*>(&Ws[(k + KK) * DIM + cbase + 0]);   \
    const float4 w1 =                                                        \
        *reinterpret_cast<const float4*>(&Ws[(k + KK) * DIM + cbase + 4]);   \
    const float4 w2 =                                                        \
        *reinterpret_cast<const float4*>(&Ws[(k + KK) * DIM + cbase + 8]);   \
    FMA4(c00, A0, w0); FMA4(c01, A0, w1); FMA4(c02, A0, w2);                 \
    FMA4(c10, A1, w0); FMA4(c11, A1, w1); FMA4(c12, A1, w2);                 \
    FMA4(c20, A2, w0); FMA4(c21, A2, w1); FMA4(c22, A2, w2);                 \
    FMA4(c30, A3, w0); FMA4(c31, A3, w1); FMA4(c32, A3, w2);                 \
  }

#define COMPUTE_CHUNK(STRIDE, KOFF)                                          \
  _Pragma("unroll") for (int k = 0; k < BK; k += 4) {                        \
    const float4 av0 = *reinterpret_cast<const float4*>(                     \
        &AH[(r0 + 0) * STRIDE + KOFF + k]);                                  \
    const float4 av1 = *reinterpret_cast<const float4*>(                     \
        &AH[(r0 + 1) * STRIDE + KOFF + k]);                                  \
    const float4 av2 = *reinterpret_cast<const float4*>(                     \
        &AH[(r0 + 2) * STRIDE + KOFF + k]);                                  \
    const float4 av3 = *reinterpret_cast<const float4*>(                     \
        &AH[(r0 + 3) * STRIDE + KOFF + k]);                                  \
    KQ(0, av0.x, av1.x, av2.x, av3.x);                                       \
    KQ(1, av0.y, av1.y, av2.y, av3.y);                                       \
    KQ(2, av0.z, av1.z, av2.z, av3.z);                                       \
    KQ(3, av0.w, av1.w, av2.w, av3.w);                                       \
  }

#define ZERO_ACC()                                          \
  c00 = make_float4(0.f, 0.f, 0.f, 0.f);                    \
  c01 = c00; c02 = c00; c10 = c00; c11 = c00; c12 = c00;    \
  c20 = c00; c21 = c00; c22 = c00; c30 = c00; c31 = c00;    \
  c32 = c00;

// ---------------------------------------------------------------------------
// CSR build stage 1: per-destination histogram.
// ---------------------------------------------------------------------------
__global__ __launch_bounds__(256) void hist_kernel(const int* __restrict__ ei,
                                                   int* __restrict__ sc) {
  int e = blockIdx.x * 256 + threadIdx.x;
  if (e < N_EDGES) atomicAdd(&sc[SC_CNT + ei[N_EDGES + e]], 1);
}

// ---------------------------------------------------------------------------
// CSR build stage 2a: per-block sums of the histogram.
// ---------------------------------------------------------------------------
__global__ __launch_bounds__(256) void scan1_kernel(int* __restrict__ sc) {
  __shared__ int s[256];
  int i = blockIdx.x * 256 + threadIdx.x;
  s[threadIdx.x] = (i < N_NODES) ? sc[SC_CNT + i] : 0;
  __syncthreads();
  for (int off = 128; off > 0; off >>= 1) {
    if (threadIdx.x < off) s[threadIdx.x] += s[threadIdx.x + off];
    __syncthreads();
  }
  if (threadIdx.x == 0) sc[SC_BSUM + blockIdx.x] = s[0];
}

// ---------------------------------------------------------------------------
// CSR build stage 2b: exclusive scan of the 196 block sums (single block).
// ---------------------------------------------------------------------------
__global__ __launch_bounds__(256) void scan2_kernel(int* __restrict__ sc) {
  __shared__ int s[2][256];
  const int t = threadIdx.x;
  const int v = (t < NBLK_SCAN) ? sc[SC_BSUM + t] : 0;
  int cur = 0;
  s[0][t] = v;
  __syncthreads();
  for (int off = 1; off < 256; off <<= 1) {
    int nv = s[cur][t];
    if (t >= off) nv += s[cur][t - off];
    s[cur ^ 1][t] = nv;
    cur ^= 1;
    __syncthreads();
  }
  if (t < NBLK_SCAN) sc[SC_BSUM + t] = s[cur][t] - v;  // inclusive -> exclusive
}

// ---------------------------------------------------------------------------
// CSR build stage 2c: full exclusive scan -> off[] and cur[].
// ---------------------------------------------------------------------------
__global__ __launch_bounds__(256) void scan3_kernel(int* __restrict__ sc) {
  __shared__ int s[2][256];
  const int t = threadIdx.x;
  const int i = blockIdx.x * 256 + t;
  const int v = (i < N_NODES) ? sc[SC_CNT + i] : 0;
  int cur = 0;
  s[0][t] = v;
  __syncthreads();
  for (int off = 1; off < 256; off <<= 1) {
    int nv = s[cur][t];
    if (t >= off) nv += s[cur][t - off];
    s[cur ^ 1][t] = nv;
    cur ^= 1;
    __syncthreads();
  }
  if (i < N_NODES) {
    const int excl = sc[SC_BSUM + blockIdx.x] + s[cur][t] - v;
    sc[SC_OFF + i] = excl;
    sc[SC_CUR + i] = excl;
  }
  if (i == 0) sc[SC_OFF + N_NODES] = N_EDGES;
}

// ---------------------------------------------------------------------------
// CSR build stage 3: fill edge-id lists (sorted by destination).
// ---------------------------------------------------------------------------
__global__ __launch_bounds__(256) void fill_kernel(const int* __restrict__ ei,
                                                   int* __restrict__ sc) {
  int e = blockIdx.x * 256 + threadIdx.x;
  if (e < N_EDGES) {
    const int d = ei[N_EDGES + e];
    const int pos = atomicAdd(&sc[SC_CUR + d], 1);
    sc[SC_EIDX + pos] = e;
  }
}

// ---------------------------------------------------------------------------
// Gather: agg[n] = sum of edge_attr rows with dst == n. Atomic-free.
// ---------------------------------------------------------------------------
__global__ __launch_bounds__(192) void gather_kernel(
    const float* __restrict__ ea, const int* __restrict__ sc,
    float* __restrict__ agg) {
  const int t = threadIdx.x;
  const int ln = t / 24;
  const int q = t - ln * 24;
  const int n = blockIdx.x * 8 + ln;
  const int beg = sc[SC_OFF + n];
  const int end = sc[SC_OFF + n + 1];
  float4 acc = make_float4(0.f, 0.f, 0.f, 0.f);
  int e = (beg < end) ? sc[SC_EIDX + beg] : 0;
  for (int i = beg; i < end; ++i) {
    const int en = (i + 1 < end) ? sc[SC_EIDX + i + 1] : 0;
    const float4 v =
        *reinterpret_cast<const float4*>(ea + (size_t)e * DIM + q * 4);
    acc.x += v.x;
    acc.y += v.y;
    acc.z += v.z;
    acc.w += v.w;
    e = en;
  }
  *reinterpret_cast<float4*>(agg + (size_t)n * DIM + q * 4) = acc;
}

// ---------------------------------------------------------------------------
// Copy edge_index to output as floats.
// ---------------------------------------------------------------------------
__global__ __launch_bounds__(256) void copy_ei_kernel(
    const int* __restrict__ ei, float* __restrict__ out) {
  int tid = blockIdx.x * 256 + threadIdx.x;
  if (tid < 2 * N_EDGES) out[tid] = (float)ei[tid];
}

// ---------------------------------------------------------------------------
// Node MLP: 128-row tile, 4x12 register tile, register-prefetched staging.
// LDS = Ws 18KB + AH 51.2KB = 69.2KB -> 2 blocks/CU.
// ---------------------------------------------------------------------------
__global__ __launch_bounds__(256, 2) void node_mlp_kernel(
    const float* __restrict__ x, const float* __restrict__ agg,
    const float* __restrict__ W1, const float* __restrict__ b1,
    const float* __restrict__ W2, const float* __restrict__ b2,
    float* __restrict__ out) {
  __shared__ float Ws[BK * DIM];
  __shared__ float AH[BM * HPAD];

  const int t = threadIdx.x;
  const int tx = t & 7;
  const int ty = t >> 3;
  const int r0 = ty * 4;
  const int n0 = blockIdx.x * BM;
  const int cbase = tx * 12;

  int arow[6], acol[6];
#pragma unroll
  for (int m = 0; m < 6; ++m) {
    const int idx = m * 256 + t;
    arow[m] = idx / 12;
    acol[m] = (idx - arow[m] * 12) * 4;
  }
  int wr[5], wc[5];
#pragma unroll
  for (int m = 0; m < 5; ++m) {
    const int idx = m * 256 + t;
    wr[m] = idx / 24;
    wc[m] = (idx - wr[m] * 24) * 4;
  }

  float4 ra[6], rw[5];

  auto load_a = [&](int ch) {
#pragma unroll
    for (int m = 0; m < 6; ++m) {
      const int col = ch * BK + acol[m];
      int n = n0 + arow[m];
      n = (n < N_NODES) ? n : 0;  // clamp; garbage rows never stored
      const float* p = (col < DIM) ? x + (size_t)n * DIM + col
                                   : agg + (size_t)n * DIM + (col - DIM);
      ra[m] = *reinterpret_cast<const float4*>(p);
    }
  };
  auto load_w = [&](const float* W, int ch) {
#pragma unroll
    for (int m = 0; m < 5; ++m)
      if (m < 4 || t < 128)
        rw[m] = *reinterpret_cast<const float4*>(
            W + (size_t)(ch * BK + wr[m]) * DIM + wc[m]);
  };
  auto store_a = [&]() {
#pragma unroll
    for (int m = 0; m < 6; ++m)
      *reinterpret_cast<float4*>(&AH[arow[m] * APAD + acol[m]]) = ra[m];
  };
  auto store_w = [&]() {
#pragma unroll
    for (int m = 0; m < 5; ++m)
      if (m < 4 || t < 128)
        *reinterpret_cast<float4*>(&Ws[wr[m] * DIM + wc[m]]) = rw[m];
  };

  float4 c00, c01, c02, c10, c11, c12, c20, c21, c22, c30, c31, c32;
  ZERO_ACC();

  // ----- layer 1: K=192, 4 chunks of 48; prefetch next chunk into regs -----
  load_a(0);
  load_w(W1, 0);
  for (int ch = 0; ch < 4; ++ch) {
    store_a();
    store_w();
    __syncthreads();
    if (ch < 3) {
      load_a(ch + 1);
      load_w(W1, ch + 1);
    } else {
      load_w(W2, 0);  // prefetch W2 chunk 0 under the last L1 compute
    }
    COMPUTE_CHUNK(APAD, 0);
    __syncthreads();
  }

  // bias + relu -> H (HPAD view of AH)
  {
    const float4 bb0 = *reinterpret_cast<const float4*>(b1 + cbase + 0);
    const float4 bb1 = *reinterpret_cast<const float4*>(b1 + cbase + 4);
    const float4 bb2 = *reinterpret_cast<const float4*>(b1 + cbase + 8);
    BIAS_RELU4(c00, bb0); BIAS_RELU4(c01, bb1); BIAS_RELU4(c02, bb2);
    BIAS_RELU4(c10, bb0); BIAS_RELU4(c11, bb1); BIAS_RELU4(c12, bb2);
    BIAS_RELU4(c20, bb0); BIAS_RELU4(c21, bb1); BIAS_RELU4(c22, bb2);
    BIAS_RELU4(c30, bb0); BIAS_RELU4(c31, bb1); BIAS_RELU4(c32, bb2);
    *reinterpret_cast<float4*>(&AH[(r0 + 0) * HPAD + cbase + 0]) = c00;
    *reinterpret_cast<float4*>(&AH[(r0 + 0) * HPAD + cbase + 4]) = c01;
    *reinterpret_cast<float4*>(&AH[(r0 + 0) * HPAD + cbase + 8]) = c02;
    *reinterpret_cast<float4*>(&AH[(r0 + 1) * HPAD + cbase + 0]) = c10;
    *reinterpret_cast<float4*>(&AH[(r0 + 1) * HPAD + cbase + 4]) = c11;
    *reinterpret_cast<float4*>(&AH[(r0 + 1) * HPAD + cbase + 8]) = c12;
    *reinterpret_cast<float4*>(&AH[(r0 + 2) * HPAD + cbase + 0]) = c20;
    *reinterpret_cast<float4*>(&AH[(r0 + 2) * HPAD + cbase + 4]) = c21;
    *reinterpret_cast<float4*>(&AH[(r0 + 2) * HPAD + cbase + 8]) = c22;
    *reinterpret_cast<float4*>(&AH[(r0 + 3) * HPAD + cbase + 0]) = c30;
    *reinterpret_cast<float4*>(&AH[(r0 + 3) * HPAD + cbase + 4]) = c31;
    *reinterpret_cast<float4*>(&AH[(r0 + 3) * HPAD + cbase + 8]) = c32;
  }
  store_w();  // W2 chunk 0
  __syncthreads();

  // ----- layer 2: K=96, 2 chunks -----
  load_w(W2, 1);
  ZERO_ACC();
  COMPUTE_CHUNK(HPAD, 0);
  __syncthreads();
  store_w();  // W2 chunk 1
  __syncthreads();
  COMPUTE_CHUNK(HPAD, BK);

  {
    const float4 bb0 = *reinterpret_cast<const float4*>(b2 + cbase + 0);
    const float4 bb1 = *reinterpret_cast<const float4*>(b2 + cbase + 4);
    const float4 bb2 = *reinterpret_cast<const float4*>(b2 + cbase + 8);
    BIAS4(c00, bb0); BIAS4(c01, bb1); BIAS4(c02, bb2);
    BIAS4(c10, bb0); BIAS4(c11, bb1); BIAS4(c12, bb2);
    BIAS4(c20, bb0); BIAS4(c21, bb1); BIAS4(c22, bb2);
    BIAS4(c30, bb0); BIAS4(c31, bb1); BIAS4(c32, bb2);
    if (n0 + r0 + 0 < N_NODES) {
      float* o = out + (size_t)(n0 + r0 + 0) * DIM + cbase;
      *reinterpret_cast<float4*>(o + 0) = c00;
      *reinterpret_cast<float4*>(o + 4) = c01;
      *reinterpret_cast<float4*>(o + 8) = c02;
    }
    if (n0 + r0 + 1 < N_NODES) {
      float* o = out + (size_t)(n0 + r0 + 1) * DIM + cbase;
      *reinterpret_cast<float4*>(o + 0) = c10;
      *reinterpret_cast<float4*>(o + 4) = c11;
      *reinterpret_cast<float4*>(o + 8) = c12;
    }
    if (n0 + r0 + 2 < N_NODES) {
      float* o = out + (size_t)(n0 + r0 + 2) * DIM + cbase;
      *reinterpret_cast<float4*>(o + 0) = c20;
      *reinterpret_cast<float4*>(o + 4) = c21;
      *reinterpret_cast<float4*>(o + 8) = c22;
    }
    if (n0 + r0 + 3 < N_NODES) {
      float* o = out + (size_t)(n0 + r0 + 3) * DIM + cbase;
      *reinterpret_cast<float4*>(o + 0) = c30;
      *reinterpret_cast<float4*>(o + 4) = c31;
      *reinterpret_cast<float4*>(o + 8) = c32;
    }
  }
}

// ---------------------------------------------------------------------------
// Edge MLP: 128-row tile, 4x12 register tile, register-prefetched staging.
// K=288 (x[src] || x[dst] || ea), 6 chunks; each chunk within one segment.
// N_EDGES % 128 == 0 -> no row guards. Runs LAST: overwrites CSR scratch.
// ---------------------------------------------------------------------------
__global__ __launch_bounds__(256, 2) void edge_mlp_kernel(
    const float* __restrict__ x, const int* __restrict__ ei,
    const float* __restrict__ ea, const float* __restrict__ W1,
    const float* __restrict__ b1, const float* __restrict__ W2,
    const float* __restrict__ b2, float* __restrict__ out) {
  __shared__ int s_src[BM];
  __shared__ int s_dst[BM];
  __shared__ float Ws[BK * DIM];
  __shared__ float AH[BM * HPAD];

  const int t = threadIdx.x;
  const int tx = t & 7;
  const int ty = t >> 3;
  const int r0 = ty * 4;
  const int e0 = blockIdx.x * BM;
  const int cbase = tx * 12;

  int arow[6], acol[6];
#pragma unroll
  for (int m = 0; m < 6; ++m) {
    const int idx = m * 256 + t;
    arow[m] = idx / 12;
    acol[m] = (idx - arow[m] * 12) * 4;
  }
  int wr[5], wc[5];
#pragma unroll
  for (int m = 0; m < 5; ++m) {
    const int idx = m * 256 + t;
    wr[m] = idx / 24;
    wc[m] = (idx - wr[m] * 24) * 4;
  }

  if (t < BM)
    s_src[t] = ei[e0 + t];
  else
    s_dst[t - BM] = ei[N_EDGES + e0 + (t - BM)];
  __syncthreads();

  float4 ra[6], rw[5];

  auto load_a = [&](int ch) {
#pragma unroll
    for (int m = 0; m < 6; ++m) {
      const int col = ch * BK + acol[m];
      const int row = arow[m];
      const float* p;
      if (col < DIM)
        p = x + (size_t)s_src[row] * DIM + col;
      else if (col < 2 * DIM)
        p = x + (size_t)s_dst[row] * DIM + (col - DIM);
      else
        p = ea + (size_t)(e0 + row) * DIM + (col - 2 * DIM);
      ra[m] = *reinterpret_cast<const float4*>(p);
    }
  };
  auto load_w = [&](const float* W, int ch) {
#pragma unroll
    for (int m = 0; m < 5; ++m)
      if (m < 4 || t < 128)
        rw[m] = *reinterpret_cast<const float4*>(
            W + (size_t)(ch * BK + wr[m]) * DIM + wc[m]);
  };
  auto store_a = [&]() {
#pragma unroll
    for (int m = 0; m < 6; ++m)
      *reinterpret_cast<float4*>(&AH[arow[m] * APAD + acol[m]]) = ra[m];
  };
  auto store_w = [&]() {
#pragma unroll
    for (int m = 0; m < 5; ++m)
      if (m < 4 || t < 128)
        *reinterpret_cast<float4*>(&Ws[wr[m] * DIM + wc[m]]) = rw[m];
  };

  float4 c00, c01, c02, c10, c11, c12, c20, c21, c22, c30, c31, c32;
  ZERO_ACC();

  // ----- layer 1: 6 chunks of 48; prefetch next chunk into regs -----
  load_a(0);
  load_w(W1, 0);
  for (int ch = 0; ch < 6; ++ch) {
    store_a();
    store_w();
    __syncthreads();
    if (ch < 5) {
      load_a(ch + 1);
      load_w(W1, ch + 1);
    } else {
      load_w(W2, 0);  // prefetch W2 chunk 0 under the last L1 compute
    }
    COMPUTE_CHUNK(APAD, 0);
    __syncthreads();
  }

  // bias + relu -> H
  {
    const float4 bb0 = *reinterpret_cast<const float4*>(b1 + cbase + 0);
    const float4 bb1 = *reinterpret_cast<const float4*>(b1 + cbase + 4);
    const float4 bb2 = *reinterpret_cast<const float4*>(b1 + cbase + 8);
    BIAS_RELU4(c00, bb0); BIAS_RELU4(c01, bb1); BIAS_RELU4(c02, bb2);
    BIAS_RELU4(c10, bb0); BIAS_RELU4(c11, bb1); BIAS_RELU4(c12, bb2);
    BIAS_RELU4(c20, bb0); BIAS_RELU4(c21, bb1); BIAS_RELU4(c22, bb2);
    BIAS_RELU4(c30, bb0); BIAS_RELU4(c31, bb1); BIAS_RELU4(c32, bb2);
    *reinterpret_cast<float4*>(&AH[(r0 + 0) * HPAD + cbase + 0]) = c00;
    *reinterpret_cast<float4*>(&AH[(r0 + 0) * HPAD + cbase + 4]) = c01;
    *reinterpret_cast<float4*>(&AH[(r0 + 0) * HPAD + cbase + 8]) = c02;
    *reinterpret_cast<float4*>(&AH[(r0 + 1) * HPAD + cbase + 0]) = c10;
    *reinterpret_cast<float4*>(&AH[(r0 + 1) * HPAD + cbase + 4]) = c11;
    *reinterpret_cast<float4*>(&AH[(r0 + 1) * HPAD + cbase + 8]) = c12;
    *reinterpret_cast<float4*>(&AH[(r0 + 2) * HPAD + cbase + 0]) = c20;
    *reinterpret_cast<float4*>(&AH[(r0 + 2) * HPAD + cbase + 4]) = c21;
    *reinterpret_cast<float4*>(&AH[(r0 + 2) * HPAD + cbase + 8]) = c22;
    *reinterpret_cast<float4*>(&AH[(r0 + 3) * HPAD + cbase + 0]) = c30;
    *reinterpret_cast<float4*>(&AH[(r0 + 3) * HPAD + cbase + 4]) = c31;
    *reinterpret_cast<float4*>(&AH[(r0 + 3) * HPAD + cbase + 8]) = c32;
  }
  store_w();  // W2 chunk 0
  __syncthreads();

  // ----- layer 2 -----
  load_w(W2, 1);
  ZERO_ACC();
  COMPUTE_CHUNK(HPAD, 0);
  __syncthreads();
  store_w();  // W2 chunk 1
  __syncthreads();
  COMPUTE_CHUNK(HPAD, BK);

  {
    const float4 bb0 = *reinterpret_cast<const float4*>(b2 + cbase + 0);
    const float4 bb1 = *reinterpret_cast<const float4*>(b2 + cbase + 4);
    const float4 bb2 = *reinterpret_cast<const float4*>(b2 + cbase + 8);
    BIAS4(c00, bb0); BIAS4(c01, bb1); BIAS4(c02, bb2);
    BIAS4(c10, bb0); BIAS4(c11, bb1); BIAS4(c12, bb2);
    BIAS4(c20, bb0); BIAS4(c21, bb1); BIAS4(c22, bb2);
    BIAS4(c30, bb0); BIAS4(c31, bb1); BIAS4(c32, bb2);
    float* o0 = out + (size_t)(e0 + r0 + 0) * DIM + cbase;
    float* o1 = out + (size_t)(e0 + r0 + 1) * DIM + cbase;
    float* o2 = out + (size_t)(e0 + r0 + 2) * DIM + cbase;
    float* o3 = out + (size_t)(e0 + r0 + 3) * DIM + cbase;
    *reinterpret_cast<float4*>(o0 + 0) = c00;
    *reinterpret_cast<float4*>(o0 + 4) = c01;
    *reinterpret_cast<float4*>(o0 + 8) = c02;
    *reinterpret_cast<float4*>(o1 + 0) = c10;
    *reinterpret_cast<float4*>(o1 + 4) = c11;
    *reinterpret_cast<float4*>(o1 + 8) = c12;
    *reinterpret_cast<float4*>(o2 + 0) = c20;
    *reinterpret_cast<float4*>(o2 + 4) = c21;
    *reinterpret_cast<float4*>(o2 + 8) = c22;
    *reinterpret_cast<float4*>(o3 + 0) = c30;
    *reinterpret_cast<float4*>(o3 + 4) = c31;
    *reinterpret_cast<float4*>(o3 + 8) = c32;
  }
}

// ---------------------------------------------------------------------------
extern "C" void kernel_launch(void* const* d_in, const int* in_sizes, int n_in,
                              void* d_out, int out_size, void* d_ws,
                              size_t ws_size, hipStream_t stream) {
  const float* x = (const float*)d_in[0];
  const int* ei = (const int*)d_in[1];
  const float* edge_attr = (const float*)d_in[2];
  const float* Wn1 = (const float*)d_in[3];
  const float* bn1 = (const float*)d_in[4];
  const float* Wn2 = (const float*)d_in[5];
  const float* bn2 = (const float*)d_in[6];
  const float* We1 = (const float*)d_in[7];
  const float* be1 = (const float*)d_in[8];
  const float* We2 = (const float*)d_in[9];
  const float* be2 = (const float*)d_in[10];

  float* out = (float*)d_out;
  float* agg = (float*)d_ws;  // [N_NODES, DIM] fp32 scratch = 19.2 MB

  float* out_hv = out;
  float* out_ei = out + (size_t)N_NODES * DIM;
  float* out_he = out + (size_t)N_NODES * DIM + 2 * (size_t)N_EDGES;

  // CSR scratch lives in the out_he region (< 4 MB of its 307 MB); the
  // edge_mlp_kernel runs last and overwrites the entire region with h_e.
  int* sc = (int*)out_he;

  hipMemsetAsync(sc + SC_CNT, 0, N_NODES * sizeof(int), stream);
  hist_kernel<<<(N_EDGES + 255) / 256, 256, 0, stream>>>(ei, sc);
  scan1_kernel<<<NBLK_SCAN, 256, 0, stream>>>(sc);
  scan2_kernel<<<1, 256, 0, stream>>>(sc);
  scan3_kernel<<<NBLK_SCAN, 256, 0, stream>>>(sc);
  fill_kernel<<<(N_EDGES + 255) / 256, 256, 0, stream>>>(ei, sc);
  gather_kernel<<<N_NODES / 8, 192, 0, stream>>>(edge_attr, sc, agg);

  copy_ei_kernel<<<(2 * N_EDGES + 255) / 256, 256, 0, stream>>>(ei, out_ei);
  node_mlp_kernel<<<(N_NODES + BM - 1) / BM, 256, 0, stream>>>(
      x, agg, Wn1, bn1, Wn2, bn2, out_hv);
  edge_mlp_kernel<<<N_EDGES / BM, 256, 0, stream>>>(x, ei, edge_attr, We1, be1,
                                                    We2, be2, out_he);
}